// Round 20
// baseline (215.260 us; speedup 1.0000x reference)
//
#include <hip/hip_runtime.h>
#include <stdint.h>

// Shapes are fixed by the reference: B=2, T=2048, C=1024, H=16, Dh=64.
#define B_   2
#define T_   2048
#define C_   1024
#define H_   16
#define BT   4096      // B_*T_
#define KDIM 1024      // inner dim of all projections

typedef unsigned short u16;
typedef __attribute__((ext_vector_type(8))) __bf16 bf16v8;   // 4 VGPR MFMA operand
typedef __attribute__((ext_vector_type(4))) float f32x4;     // 16x16 accumulator
typedef __attribute__((ext_vector_type(16))) float f32x16;   // 32x32 accumulator
typedef __attribute__((ext_vector_type(4))) unsigned int u32x4;
typedef __attribute__((ext_vector_type(2))) unsigned int u32x2;

#define MFMA16(a, b, c) __builtin_amdgcn_mfma_f32_16x16x32_bf16((a), (b), (c), 0, 0, 0)
#define MFMA32(a, b, c) __builtin_amdgcn_mfma_f32_32x32x16_bf16((a), (b), (c), 0, 0, 0)

#define BARRIER() do { asm volatile("" ::: "memory"); \
                       __builtin_amdgcn_s_barrier();  \
                       asm volatile("" ::: "memory"); } while (0)

__device__ __forceinline__ u16 f2bf(float f) {
  __bf16 h = (__bf16)f;                       // native v_cvt (RNE)
  union { __bf16 h; u16 u; } v; v.h = h;
  return v.u;
}
__device__ __forceinline__ float bf2f(u16 u) {
  union { uint32_t u; float f; } v; v.u = (uint32_t)u << 16;
  return v.f;
}

// cross-half exchange: returns lo = {a_lo, b_lo}, hi = {a_hi, b_hi}.
// Intrinsic form (two results) -> distinct dest regs guaranteed (R9 lesson).
__device__ __forceinline__ void xhalf(uint32_t a, uint32_t b,
                                      uint32_t& lo, uint32_t& hi) {
#if defined(__has_builtin) && __has_builtin(__builtin_amdgcn_permlane32_swap)
  u32x2 r = __builtin_amdgcn_permlane32_swap(a, b, false, false);
  lo = r.x; hi = r.y;
#else
  const bool upper = (threadIdx.x & 32) != 0;
  lo = upper ? __shfl_xor(b, 32) : a;
  hi = upper ? b : __shfl_xor(a, 32);
#endif
}

// async global->LDS, 16B per lane; LDS dest is wave-uniform base + lane*16
__device__ __forceinline__ void gload16(const void* g, void* l) {
  __builtin_amdgcn_global_load_lds((__attribute__((address_space(1))) void*)g,
                                   (__attribute__((address_space(3))) void*)l,
                                   16, 0, 0);
}

// ---------------------------------------------------------------- fp32->bf16
// single launch: blocks 0..4095 convert x; 4096..8191 convert the 4 weights
__global__ __launch_bounds__(256) void cvt_all(
    const float* __restrict__ x,
    const float* __restrict__ wq, const float* __restrict__ wk,
    const float* __restrict__ wv, const float* __restrict__ wo,
    u16* __restrict__ xb, u16* __restrict__ qkv_dst, u16* __restrict__ o_dst) {
  const int bid = blockIdx.x;
  const float* src;
  u16* dst;
  int i;
  if (bid < 4096) {
    src = x; dst = xb;
    i = (bid * 256 + threadIdx.x) * 4;
  } else {
    const int b2 = bid - 4096;
    const int sel = b2 >> 10;
    src = (sel == 0) ? wq : (sel == 1) ? wk : (sel == 2) ? wv : wo;
    dst = (sel < 3) ? (qkv_dst + sel * 1048576) : o_dst;
    i = ((b2 & 1023) * 256 + threadIdx.x) * 4;
  }
  float4 v = *(const float4*)(src + i);
  ushort4 o;
  o.x = f2bf(v.x); o.y = f2bf(v.y); o.z = f2bf(v.z); o.w = f2bf(v.w);
  *(ushort4*)(dst + i) = o;
}

// ---------------------------------------------------------------- QKV GEMM
// (R16-18 proven plateau: 128x128 tile, BK=32, 32KB LDS, 3 blocks/CU,
// counted vmcnt(4), locality XCD swizzle, 2-bit XOR swizzle, RoPE + V^T.)
__global__ __launch_bounds__(256, 2) void gemm_qkv32(
    const u16* __restrict__ A, const u16* __restrict__ Bm,
    u16* __restrict__ qo, u16* __restrict__ ko, u16* __restrict__ vt,
    const float* __restrict__ cosT, const float* __restrict__ sinT)
{
  __shared__ __align__(16) char smem[32768];   // As[2] @0, Bs[2] @16384 (8KB each)
  const int tid = threadIdx.x;
  const int lane = tid & 63;
  const int w = tid >> 6;
  const int wm = w >> 1, wn = w & 1;
  const int lmod = lane & 15, ldiv = lane >> 4;

  // locality-first XCD swizzle: per XCD 8by x 12bx (A 2MB + B 3MB ~ L2)
  const int x = blockIdx.x & 7;
  const int i = blockIdx.x >> 3;               // 0..95
  const int by = (x >> 1) * 8 + (i % 8);
  const int bx = (x & 1) * 12 + (i / 8);
  const int row0 = by * 128, col0 = bx * 128;

  const int ldst = (tid & 192) * 16;           // wave-uniform LDS sub-base

  auto stage = [&](int buf, int t) {
    const int kb = t * 64;                     // BK=32 -> 64B per row per tile
#pragma unroll
    for (int c = 0; c < 2; ++c) {
      const int chunk = c * 256 + tid;
      const int row = chunk >> 2;
      const int col = ((chunk & 3) * 16) ^ ((row & 3) << 4);   // inv-swizzled src
      gload16((const char*)A + (size_t)(row0 + row) * 2048 + kb + col,
              smem + buf * 8192 + c * 4096 + ldst);
      gload16((const char*)Bm + (size_t)(col0 + row) * 2048 + kb + col,
              smem + 16384 + buf * 8192 + c * 4096 + ldst);
    }
  };

  f32x4 acc[4][4] = {};
  stage(0, 0);

  for (int t = 0; t < 32; ++t) {
    const int cur = t & 1;
    BARRIER();                                 // all waves done reading buf[cur^1]
    if (t + 1 < 32) {
      stage(cur ^ 1, t + 1);                   // 4 loads for t+1 in flight
      asm volatile("s_waitcnt vmcnt(4)" ::: "memory");   // tile t landed
    } else {
      asm volatile("s_waitcnt vmcnt(0)" ::: "memory");
    }
    BARRIER();                                 // cross-wave: tile t visible

    bf16v8 af[4], bfr[4];
#pragma unroll
    for (int mf = 0; mf < 4; ++mf) {
      const int rr = wm * 64 + mf * 16 + lmod;
      af[mf] = *(const bf16v8*)(smem + cur * 8192 + rr * 64 +
                    ((ldiv * 16) ^ ((rr & 3) << 4)));
    }
#pragma unroll
    for (int nf = 0; nf < 4; ++nf) {
      const int rr = wn * 64 + nf * 16 + lmod;
      bfr[nf] = *(const bf16v8*)(smem + 16384 + cur * 8192 + rr * 64 +
                    ((ldiv * 16) ^ ((rr & 3) << 4)));
    }
#pragma unroll
    for (int mf = 0; mf < 4; ++mf)
#pragma unroll
      for (int nf = 0; nf < 4; ++nf)
        acc[mf][nf] = MFMA16(af[mf], bfr[nf], acc[mf][nf]);
  }

  // epilogue: wave's 64-col block is head-aligned
  const int nb = col0 + wn * 64;
  const int proj = nb >> 10;            // 0=q 1=k 2=v  (block-uniform)
  const int hh = (nb & 1023) >> 6;      // head
  if (proj < 2) {
    u16* dst = proj ? ko : qo;
#pragma unroll
    for (int mf = 0; mf < 4; ++mf) {
#pragma unroll
      for (int r = 0; r < 4; ++r) {
        const int m = row0 + wm * 64 + mf * 16 + ldiv * 4 + r;
        const int b = m >> 11, t = m & 2047;
        u16* drow = dst + ((size_t)(b * H_ + hh) * T_ + t) * 64;
#pragma unroll
        for (int nf = 0; nf < 4; ++nf) {
          const int d = nf * 16 + lmod;
          const float cs = cosT[t * 64 + d];
          const float sn = sinT[t * 64 + d];
          const float other = (nf < 2) ? acc[mf][nf + 2][r] : acc[mf][nf - 2][r];
          float val = (nf < 2) ? (acc[mf][nf][r] * cs - other * sn)
                               : (acc[mf][nf][r] * cs + other * sn);
          if (proj == 0) val *= 0.18033688011112042f;  // 0.125 * log2(e)
          drow[d] = f2bf(val);
        }
      }
    }
  } else {
    // V^T direct: LDS bounce [d][t] (XOR-swizzled), then coalesced 128B rows
    BARRIER();                          // everyone done with the ring
    char* scr = smem + w * 8192;        // 8 KB per wave (spans As+Bs)
#pragma unroll
    for (int nf = 0; nf < 4; ++nf)
#pragma unroll
      for (int mf = 0; mf < 4; ++mf)
#pragma unroll
        for (int rp = 0; rp < 2; ++rp) {
          const int dd = nf * 16 + lmod;
          const int t0 = mf * 16 + ldiv * 4 + rp * 2;
          const uint32_t pk = (uint32_t)f2bf(acc[mf][nf][rp * 2]) |
                              ((uint32_t)f2bf(acc[mf][nf][rp * 2 + 1]) << 16);
          *(uint32_t*)(scr + ((dd * 128 + t0 * 2) ^ ((dd & 7) << 4))) = pk;
        }
    __syncthreads();
    const int trow = row0 + wm * 64;    // this wave's 64 t-values
    const int bb = trow >> 11, tl = trow & 2047;
#pragma unroll
    for (int j = 0; j < 8; ++j) {
      const int dd = j * 8 + (lane >> 3);
      const int c = lane & 7;
      const u32x4 vv = *(const u32x4*)(scr + ((dd * 128 + c * 16) ^ ((dd & 7) << 4)));
      u16* drow = vt + ((size_t)((bb * H_ + hh) * 64 + dd)) * T_ + tl;
      *(u32x4*)((char*)drow + c * 16) = vv;
    }
  }
}

// ---------------------------------------------------------------- GEMM 128x128
// (R13-proven BK=64 template; used for the output projection only.)
template<int NN>
__global__ __launch_bounds__(256, 2) void gemm128(
    const u16* __restrict__ A, const u16* __restrict__ Bm,
    float* __restrict__ Cf)
{
  __shared__ __align__(16) u16 As[2][128 * 64];   // 32 KiB
  __shared__ __align__(16) u16 Bs[2][128 * 64];   // 32 KiB
  const int tid = threadIdx.x;
  const int lane = tid & 63;
  const int w = tid >> 6;
  const int wm = w >> 1, wn = w & 1;
  const int lmod = lane & 15, ldiv = lane >> 4;

  const int x = blockIdx.x & 7;
  const int i = blockIdx.x >> 3;
  const int by = x * 4 + (i % 4);
  const int bx = i / 4;
  const int row0 = by * 128, col0 = bx * 128;

  const int srow = tid >> 3;                      // 0..31
  const int sswz = ((tid & 7) * 16) ^ ((srow & 7) << 4);
  const char* Abase = (const char*)A + (size_t)(row0 + srow) * (KDIM * 2) + sswz;
  const char* Bbase = (const char*)Bm + (size_t)(col0 + srow) * (KDIM * 2) + sswz;
  const int ldst = (tid & 192) * 16;              // wave-uniform LDS sub-base

  auto stage = [&](int buf, int t) {
    const int kb = t * 128;                       // K-tile byte offset in row
#pragma unroll
    for (int c = 0; c < 4; ++c)
      gload16(Abase + (size_t)c * 32 * (KDIM * 2) + kb,
              (char*)As[buf] + c * 4096 + ldst);
#pragma unroll
    for (int c = 0; c < 4; ++c)
      gload16(Bbase + (size_t)c * 32 * (KDIM * 2) + kb,
              (char*)Bs[buf] + c * 4096 + ldst);
  };

  f32x4 acc[4][4] = {};
  stage(0, 0);

  for (int t = 0; t < KDIM / 64; ++t) {
    const int cur = t & 1;
    BARRIER();                                    // all waves done reading buf[cur^1]
    if (t + 1 < KDIM / 64) {
      stage(cur ^ 1, t + 1);                      // 8 loads for t+1 in flight
      asm volatile("s_waitcnt vmcnt(8)" ::: "memory");   // tile t landed
    } else {
      asm volatile("s_waitcnt vmcnt(0)" ::: "memory");
    }
    BARRIER();                                    // cross-wave: tile t visible

    bf16v8 af[4][2], bfr[4][2];
#pragma unroll
    for (int mf = 0; mf < 4; ++mf) {
      const int rr = wm * 64 + mf * 16 + lmod;
#pragma unroll
      for (int kc = 0; kc < 2; ++kc)
        af[mf][kc] = *(const bf16v8*)((const char*)As[cur] + rr * 128 +
                          ((kc * 64 + ldiv * 16) ^ ((rr & 7) << 4)));
    }
#pragma unroll
    for (int nf = 0; nf < 4; ++nf) {
      const int rr = wn * 64 + nf * 16 + lmod;
#pragma unroll
      for (int kc = 0; kc < 2; ++kc)
        bfr[nf][kc] = *(const bf16v8*)((const char*)Bs[cur] + rr * 128 +
                          ((kc * 64 + ldiv * 16) ^ ((rr & 7) << 4)));
    }
#pragma unroll
    for (int kc = 0; kc < 2; ++kc)
#pragma unroll
      for (int mf = 0; mf < 4; ++mf)
#pragma unroll
        for (int nf = 0; nf < 4; ++nf)
          acc[mf][nf] = MFMA16(af[mf][kc], bfr[nf][kc], acc[mf][nf]);
  }

#pragma unroll
  for (int mf = 0; mf < 4; ++mf) {
    const int mbase = row0 + wm * 64 + mf * 16 + ldiv * 4;
#pragma unroll
    for (int nf = 0; nf < 4; ++nf) {
      const int n = col0 + wn * 64 + nf * 16 + lmod;
#pragma unroll
      for (int r = 0; r < 4; ++r)
        Cf[(size_t)(mbase + r) * NN + n] = acc[mf][nf][r];
    }
  }
}

// ---------------------------------------------------------------- attention
// Split-K flash attention, KVBLK=64 (reverted: R19's KVBLK=128 cost occupancy
// 17->14 and regressed). Heavy-first LPT dispatch, vmcnt(4). R20: combine is
// FUSED via last-arriver atomics — the second half of each split pair to
// finish performs the merge in-place (device-scope atomic + threadfence; the
// output is identical regardless of which block merges).
__global__ __launch_bounds__(256, 2) void attn_fwd4(
    const u16* __restrict__ Q, const u16* __restrict__ K,
    const u16* __restrict__ Vt, u16* __restrict__ O,
    u16* __restrict__ part_o, float* __restrict__ pml,
    unsigned int* __restrict__ cnt)
{
  __shared__ __align__(16) u16 Kl[2][64 * 64];    // 8 KiB per buffer
  __shared__ __align__(16) u16 Vl[2][64 * 64];
  __shared__ int second;
  static const int rmap[24] = {7, 22, 23, 20, 21, 6, 18, 19, 16, 17, 5, 14,
                               15, 12, 13, 4, 10, 11, 8, 9, 3, 2, 1, 0};
  const int xcd = blockIdx.x & 7;
  const int i   = blockIdx.x >> 3;          // 0..95
  const int bh  = xcd * 4 + (i & 3);
  const int r   = rmap[i >> 2];             // heavy classes first
  int qb0, t0, t1, sid;
  if (r < 8) {                              // whole chunk c = r
    qb0 = r * 128; t0 = 0; t1 = 2 * r + 2; sid = -1;
  } else {                                  // split half of chunk c = 8+(s>>1)
    const int s = r - 8;                    // 0..15
    const int c = 8 + (s >> 1);
    const int half = s & 1;
    qb0 = c * 128;
    t0 = half * (c + 1); t1 = t0 + (c + 1);
    sid = (bh * 8 + (c - 8)) * 2 + half;
  }

  const int tid = threadIdx.x, lane = tid & 63, w = tid >> 6;
  const int l31 = lane & 31, hi = lane >> 5;
  const int qrow = qb0 + w * 32;

  bf16v8 qf[4];
  {
    const u16* qp = Q + ((size_t)bh * T_ + qrow + l31) * 64 + hi * 8;
    qf[0] = *(const bf16v8*)(qp);
    qf[1] = *(const bf16v8*)(qp + 16);
    qf[2] = *(const bf16v8*)(qp + 32);
    qf[3] = *(const bf16v8*)(qp + 48);
  }

  float m2 = -1e30f, lsum = 0.f;            // log2-domain running max / sum
  f32x16 oacc0 = {}, oacc1 = {};            // O^T d-blocks 0..31 / 32..63

  const int scolb = (tid & 7) * 16;         // 16B col within 128B row
  const int ldst = (tid & 192) * 16;        // wave-uniform LDS sub-base

  auto stage = [&](int buf, int t) {
    const int s0 = t << 6;
#pragma unroll
    for (int c = 0; c < 2; ++c) {
      const int row = (c * 256 + tid) >> 3;
      const int sw = scolb ^ ((row & 7) << 4);
      gload16((const char*)(K + ((size_t)bh * T_ + s0 + row) * 64) + sw,
              (char*)Kl[buf] + c * 4096 + ldst);
    }
#pragma unroll
    for (int c = 0; c < 2; ++c) {
      const int row = (c * 256 + tid) >> 3;
      const int sw = scolb ^ ((row & 7) << 4);
      gload16((const char*)(Vt + ((size_t)(bh * 64 + row)) * T_ + s0) + sw,
              (char*)Vl[buf] + c * 4096 + ldst);
    }
  };

  auto substep = [&](int cur, int sub, int s0_sub) {
    bf16v8 kf[4], vf[4];
#pragma unroll
    for (int c = 0; c < 4; ++c) {
      const int row = sub * 32 + l31;
      kf[c] = *(const bf16v8*)((const char*)Kl[cur] + row * 128 +
                  ((c * 32 + hi * 16) ^ ((row & 7) << 4)));
    }
#pragma unroll
    for (int db = 0; db < 2; ++db)
#pragma unroll
      for (int kg = 0; kg < 2; ++kg) {
        const int row = db * 32 + l31;
        vf[db * 2 + kg] = *(const bf16v8*)((const char*)Vl[cur] + row * 128 +
                  ((sub * 64 + kg * 32 + hi * 16) ^ ((row & 7) << 4)));
      }
    f32x16 s = {};
    s = MFMA32(kf[0], qf[0], s);
    s = MFMA32(kf[1], qf[1], s);
    s = MFMA32(kf[2], qf[2], s);
    s = MFMA32(kf[3], qf[3], s);
    if (s0_sub + 31 > qrow) {               // diagonal substep: causal mask
#pragma unroll
      for (int r2 = 0; r2 < 16; ++r2) {
        const int key = s0_sub + (r2 & 3) + 8 * (r2 >> 2) + 4 * hi;
        if (key > qrow + l31) s[r2] = -1e30f;
      }
    }
    float t8[8];
#pragma unroll
    for (int r2 = 0; r2 < 8; ++r2) t8[r2] = fmaxf(s[r2], s[r2 + 8]);
    float t4a = fmaxf(t8[0], t8[4]), t4b = fmaxf(t8[1], t8[5]);
    float t4c = fmaxf(t8[2], t8[6]), t4d = fmaxf(t8[3], t8[7]);
    float pmax = fmaxf(fmaxf(t4a, t4b), fmaxf(t4c, t4d));
    {
      uint32_t lo, hh2;
      xhalf(__builtin_bit_cast(uint32_t, pmax), __builtin_bit_cast(uint32_t, pmax), lo, hh2);
      pmax = fmaxf(__builtin_bit_cast(float, lo), __builtin_bit_cast(float, hh2));
    }
    if (!__all(pmax <= m2 + 11.5416f)) {    // defer-max THR = 8*log2e
      const float mnew = fmaxf(m2, pmax);
      const float rs = __builtin_amdgcn_exp2f(m2 - mnew);
      lsum *= rs;
#pragma unroll
      for (int r2 = 0; r2 < 16; ++r2) { oacc0[r2] *= rs; oacc1[r2] *= rs; }
      m2 = mnew;
    }
    float p[16];
#pragma unroll
    for (int r2 = 0; r2 < 16; ++r2) p[r2] = __builtin_amdgcn_exp2f(s[r2] - m2);
    float a8[8];
#pragma unroll
    for (int r2 = 0; r2 < 8; ++r2) a8[r2] = p[r2] + p[r2 + 8];
    float a4a = a8[0] + a8[4], a4b = a8[1] + a8[5];
    float a4c = a8[2] + a8[6], a4d = a8[3] + a8[7];
    float ts = (a4a + a4b) + (a4c + a4d);
    {
      uint32_t lo, hh2;
      xhalf(__builtin_bit_cast(uint32_t, ts), __builtin_bit_cast(uint32_t, ts), lo, hh2);
      ts = __builtin_bit_cast(float, lo) + __builtin_bit_cast(float, hh2);
    }
    lsum += ts;
    uint32_t o[8];
#pragma unroll
    for (int jj = 0; jj < 8; ++jj) {
      const int r0 = 4 * (jj >> 1) + 2 * (jj & 1);
      uint32_t d;
      asm("v_cvt_pk_bf16_f32 %0, %1, %2" : "=v"(d) : "v"(p[r0]), "v"(p[r0 + 1]));
      o[jj] = d;
    }
#pragma unroll
    for (int kg = 0; kg < 2; ++kg) {
      uint32_t f0, f1, f2, f3;
      xhalf(o[4 * kg + 0], o[4 * kg + 2], f0, f2);
      xhalf(o[4 * kg + 1], o[4 * kg + 3], f1, f3);
      u32x4 fr;
      fr.x = f0; fr.y = f1; fr.z = f2; fr.w = f3;
      const bf16v8 pf = __builtin_bit_cast(bf16v8, fr);
      oacc0 = MFMA32(vf[kg], pf, oacc0);
      oacc1 = MFMA32(vf[2 + kg], pf, oacc1);
    }
  };

  stage(0, t0);
  for (int t = t0; t < t1; ++t) {
    const int cur = (t - t0) & 1;
    BARRIER();
    if (t + 1 < t1) {
      stage(cur ^ 1, t + 1);
      asm volatile("s_waitcnt vmcnt(4)" ::: "memory");   // tile t's 4 landed
    } else {
      asm volatile("s_waitcnt vmcnt(0)" ::: "memory");
    }
    BARRIER();
#pragma unroll
    for (int sub = 0; sub < 2; ++sub) {
      const int s0_sub = t * 64 + sub * 32;
      if (s0_sub <= qrow + 31) substep(cur, sub, s0_sub);
    }
  }

  BARRIER();                                // all waves done with Kl/Vl
  char* scr = (char*)Kl + w * 4096;         // 4 KB per wave: [q=32][d=64] bf16
  const float inv = (sid < 0) ? (1.f / lsum) : 1.f;
#pragma unroll
  for (int r2 = 0; r2 < 8; ++r2) {
    const int r = r2 * 2;                   // regs r, r+1 are adjacent d
    const int dd = (r & 3) + 8 * (r >> 2) + 4 * hi;
    const uint32_t pk0 = (uint32_t)f2bf(oacc0[r] * inv) |
                         ((uint32_t)f2bf(oacc0[r + 1] * inv) << 16);
    *(uint32_t*)(scr + ((l31 * 128 + dd * 2) ^ ((l31 & 7) << 4))) = pk0;
    const uint32_t pk1 = (uint32_t)f2bf(oacc1[r] * inv) |
                         ((uint32_t)f2bf(oacc1[r + 1] * inv) << 16);
    *(uint32_t*)(scr + ((l31 * 128 + (dd + 32) * 2) ^ ((l31 & 7) << 4))) = pk1;
  }
  __syncthreads();
  const int qq = lane >> 1, cc = lane & 1;  // 2 lanes per output row
  if (sid < 0) {
    const int b = bh >> 4, hh = bh & 15;
    u16* orow = O + ((size_t)(b * T_ + qrow + qq)) * C_ + hh * 64 + cc * 32;
#pragma unroll
    for (int jj = 0; jj < 4; ++jj) {
      const u32x4 vv = *(const u32x4*)(scr + ((qq * 128 + cc * 64 + jj * 16) ^ ((qq & 7) << 4)));
      *(u32x4*)((char*)orow + jj * 16) = vv;
    }
  } else {
    u16* prow = part_o + ((size_t)(sid * 128 + w * 32 + qq)) * 64 + cc * 32;
#pragma unroll
    for (int jj = 0; jj < 4; ++jj) {
      const u32x4 vv = *(const u32x4*)(scr + ((qq * 128 + cc * 64 + jj * 16) ^ ((qq & 7) << 4)));
      *(u32x4*)((char*)prow + jj * 16) = vv;
    }
    if (lane < 32) {                        // lanes 0..31: one per q-row
      pml[sid * 256 + w * 32 + lane] = m2;
      pml[sid * 256 + 128 + w * 32 + lane] = lsum;
    }
    // fused combine: last-arriving half merges (canonical threadfence pattern)
    const int pr = sid >> 1;                // pair index 0..255
    __threadfence();                        // my partials visible device-wide
    __syncthreads();                        // all threads' stores + fences done
    if (tid == 0) second = (atomicAdd(&cnt[pr], 1u) == 1u);
    __syncthreads();
    if (second) {
      __threadfence();                      // acquire: partner's stores visible
      const int c8 = pr & 7;
      const int sid0 = pr * 2;
      const int row = tid >> 1, dh = tid & 1;
      const float m0 = pml[sid0 * 256 + row];
      const float l0 = pml[sid0 * 256 + 128 + row];
      const float m1 = pml[(sid0 + 1) * 256 + row];
      const float l1 = pml[(sid0 + 1) * 256 + 128 + row];
      const float mm = fmaxf(m0, m1);
      const float s0 = __builtin_amdgcn_exp2f(m0 - mm);
      const float s1 = __builtin_amdgcn_exp2f(m1 - mm);
      const float minv = 1.f / (l0 * s0 + l1 * s1);
      const u16* p0 = part_o + ((size_t)(sid0 * 128 + row)) * 64 + dh * 32;
      const u16* p1 = part_o + ((size_t)((sid0 + 1) * 128 + row)) * 64 + dh * 32;
      const int b = bh >> 4, hh = bh & 15;
      const int tt = (8 + c8) * 128 + row;
      u16* dst = O + ((size_t)(b * T_ + tt)) * C_ + hh * 64 + dh * 32;
#pragma unroll
      for (int j0 = 0; j0 < 4; ++j0) {
        const u32x4 a = *(const u32x4*)(p0 + j0 * 8);
        const u32x4 bq = *(const u32x4*)(p1 + j0 * 8);
        const u16* pa = (const u16*)&a;
        const u16* pb = (const u16*)&bq;
        u16 outv[8];
#pragma unroll
        for (int j = 0; j < 8; ++j)
          outv[j] = f2bf((bf2f(pa[j]) * s0 + bf2f(pb[j]) * s1) * minv);
        *(u32x4*)(dst + j0 * 8) = *(const u32x4*)outv;
      }
    }
  }
}

// ---------------------------------------------------------------- launch
extern "C" void kernel_launch(void* const* d_in, const int* in_sizes, int n_in,
                              void* d_out, int out_size, void* d_ws, size_t ws_size,
                              hipStream_t stream) {
  const float* x    = (const float*)d_in[0];
  const float* cosT = (const float*)d_in[1];
  const float* sinT = (const float*)d_in[2];
  // d_in[3] = mask (causal by construction, unused), d_in[4] = n_heads (=16)
  const float* Wq = (const float*)d_in[5];
  const float* Wk = (const float*)d_in[6];
  const float* Wv = (const float*)d_in[7];
  const float* Wo = (const float*)d_in[8];
  float* out = (float*)d_out;

  // workspace layout (48 MB total)
  char* ws = (char*)d_ws;
  u16* xb   = (u16*)(ws);                    // bf16 x; partials alias after gemm1
  u16* wqkv = (u16*)(ws + 8388608);          // [Wq;Wk;Wv] bf16; pml aliases tail
  u16* wo   = (u16*)(ws + 14680064);         // Wo bf16
  u16* q    = (u16*)(ws + 16777216);         // (B,H,T,64) bf16, roped+scaled
  u16* k    = (u16*)(ws + 25165824);         // (B,H,T,64) bf16, roped
  u16* vt   = (u16*)(ws + 33554432);         // (B,H,64,T) bf16 (direct from gemm)
  u16* aout = (u16*)(ws + 41943040);         // attention output (B,T,C) bf16
  u16* part_o = xb;                          // 512*128*64 bf16 = 8 MB (xb dead)
  float* pml  = (float*)(ws + 8388608);      // 512*256 fp32 = 0.5 MB (wqkv dead)
  unsigned int* cnt = (unsigned int*)(ws + 8388608 + 524288);  // 256 ctrs, 1 KB

  cvt_all<<<8192, 256, 0, stream>>>(x, Wq, Wk, Wv, Wo, xb, wqkv, wo);

  gemm_qkv32<<<768, 256, 0, stream>>>(xb, wqkv, q, k, vt, cosT, sinT);
  hipMemsetAsync(cnt, 0, 1024, stream);      // zero pair counters (capture-safe)
  attn_fwd4<<<768, 256, 0, stream>>>(q, k, vt, aout, part_o, pml, cnt);
  gemm128<1024><<<256, 256, 0, stream>>>(aout, wo, out);
}

// Round 21
// 103.740 us; speedup vs baseline: 2.0750x; 2.0750x over previous
//
#include <hip/hip_runtime.h>
#include <stdint.h>

// Shapes are fixed by the reference: B=2, T=2048, C=1024, H=16, Dh=64.
#define B_   2
#define T_   2048
#define C_   1024
#define H_   16
#define BT   4096      // B_*T_
#define KDIM 1024      // inner dim of all projections

typedef unsigned short u16;
typedef __attribute__((ext_vector_type(8))) __bf16 bf16v8;   // 4 VGPR MFMA operand
typedef __attribute__((ext_vector_type(4))) float f32x4;     // 16x16 accumulator
typedef __attribute__((ext_vector_type(16))) float f32x16;   // 32x32 accumulator
typedef __attribute__((ext_vector_type(4))) unsigned int u32x4;
typedef __attribute__((ext_vector_type(2))) unsigned int u32x2;

#define MFMA16(a, b, c) __builtin_amdgcn_mfma_f32_16x16x32_bf16((a), (b), (c), 0, 0, 0)
#define MFMA32(a, b, c) __builtin_amdgcn_mfma_f32_32x32x16_bf16((a), (b), (c), 0, 0, 0)

#define BARRIER() do { asm volatile("" ::: "memory"); \
                       __builtin_amdgcn_s_barrier();  \
                       asm volatile("" ::: "memory"); } while (0)

__device__ __forceinline__ u16 f2bf(float f) {
  __bf16 h = (__bf16)f;                       // native v_cvt (RNE)
  union { __bf16 h; u16 u; } v; v.h = h;
  return v.u;
}
__device__ __forceinline__ float bf2f(u16 u) {
  union { uint32_t u; float f; } v; v.u = (uint32_t)u << 16;
  return v.f;
}

// cross-half exchange: returns lo = {a_lo, b_lo}, hi = {a_hi, b_hi}.
// Intrinsic form (two results) -> distinct dest regs guaranteed (R9 lesson).
__device__ __forceinline__ void xhalf(uint32_t a, uint32_t b,
                                      uint32_t& lo, uint32_t& hi) {
#if defined(__has_builtin) && __has_builtin(__builtin_amdgcn_permlane32_swap)
  u32x2 r = __builtin_amdgcn_permlane32_swap(a, b, false, false);
  lo = r.x; hi = r.y;
#else
  const bool upper = (threadIdx.x & 32) != 0;
  lo = upper ? __shfl_xor(b, 32) : a;
  hi = upper ? b : __shfl_xor(a, 32);
#endif
}

// async global->LDS, 16B per lane; LDS dest is wave-uniform base + lane*16
__device__ __forceinline__ void gload16(const void* g, void* l) {
  __builtin_amdgcn_global_load_lds((__attribute__((address_space(1))) void*)g,
                                   (__attribute__((address_space(3))) void*)l,
                                   16, 0, 0);
}

// ---------------------------------------------------------------- fp32->bf16
// single launch: blocks 0..4095 convert x; 4096..8191 convert the 4 weights
__global__ __launch_bounds__(256) void cvt_all(
    const float* __restrict__ x,
    const float* __restrict__ wq, const float* __restrict__ wk,
    const float* __restrict__ wv, const float* __restrict__ wo,
    u16* __restrict__ xb, u16* __restrict__ qkv_dst, u16* __restrict__ o_dst) {
  const int bid = blockIdx.x;
  const float* src;
  u16* dst;
  int i;
  if (bid < 4096) {
    src = x; dst = xb;
    i = (bid * 256 + threadIdx.x) * 4;
  } else {
    const int b2 = bid - 4096;
    const int sel = b2 >> 10;
    src = (sel == 0) ? wq : (sel == 1) ? wk : (sel == 2) ? wv : wo;
    dst = (sel < 3) ? (qkv_dst + sel * 1048576) : o_dst;
    i = ((b2 & 1023) * 256 + threadIdx.x) * 4;
  }
  float4 v = *(const float4*)(src + i);
  ushort4 o;
  o.x = f2bf(v.x); o.y = f2bf(v.y); o.z = f2bf(v.z); o.w = f2bf(v.w);
  *(ushort4*)(dst + i) = o;
}

// ---------------------------------------------------------------- QKV GEMM
// (R16-18 proven plateau: 128x128 tile, BK=32, 32KB LDS, 3 blocks/CU,
// counted vmcnt(4), locality XCD swizzle, 2-bit XOR swizzle, RoPE + V^T.)
__global__ __launch_bounds__(256, 2) void gemm_qkv32(
    const u16* __restrict__ A, const u16* __restrict__ Bm,
    u16* __restrict__ qo, u16* __restrict__ ko, u16* __restrict__ vt,
    const float* __restrict__ cosT, const float* __restrict__ sinT)
{
  __shared__ __align__(16) char smem[32768];   // As[2] @0, Bs[2] @16384 (8KB each)
  const int tid = threadIdx.x;
  const int lane = tid & 63;
  const int w = tid >> 6;
  const int wm = w >> 1, wn = w & 1;
  const int lmod = lane & 15, ldiv = lane >> 4;

  // locality-first XCD swizzle: per XCD 8by x 12bx (A 2MB + B 3MB ~ L2)
  const int x = blockIdx.x & 7;
  const int i = blockIdx.x >> 3;               // 0..95
  const int by = (x >> 1) * 8 + (i % 8);
  const int bx = (x & 1) * 12 + (i / 8);
  const int row0 = by * 128, col0 = bx * 128;

  const int ldst = (tid & 192) * 16;           // wave-uniform LDS sub-base

  auto stage = [&](int buf, int t) {
    const int kb = t * 64;                     // BK=32 -> 64B per row per tile
#pragma unroll
    for (int c = 0; c < 2; ++c) {
      const int chunk = c * 256 + tid;
      const int row = chunk >> 2;
      const int col = ((chunk & 3) * 16) ^ ((row & 3) << 4);   // inv-swizzled src
      gload16((const char*)A + (size_t)(row0 + row) * 2048 + kb + col,
              smem + buf * 8192 + c * 4096 + ldst);
      gload16((const char*)Bm + (size_t)(col0 + row) * 2048 + kb + col,
              smem + 16384 + buf * 8192 + c * 4096 + ldst);
    }
  };

  f32x4 acc[4][4] = {};
  stage(0, 0);

  for (int t = 0; t < 32; ++t) {
    const int cur = t & 1;
    BARRIER();                                 // all waves done reading buf[cur^1]
    if (t + 1 < 32) {
      stage(cur ^ 1, t + 1);                   // 4 loads for t+1 in flight
      asm volatile("s_waitcnt vmcnt(4)" ::: "memory");   // tile t landed
    } else {
      asm volatile("s_waitcnt vmcnt(0)" ::: "memory");
    }
    BARRIER();                                 // cross-wave: tile t visible

    bf16v8 af[4], bfr[4];
#pragma unroll
    for (int mf = 0; mf < 4; ++mf) {
      const int rr = wm * 64 + mf * 16 + lmod;
      af[mf] = *(const bf16v8*)(smem + cur * 8192 + rr * 64 +
                    ((ldiv * 16) ^ ((rr & 3) << 4)));
    }
#pragma unroll
    for (int nf = 0; nf < 4; ++nf) {
      const int rr = wn * 64 + nf * 16 + lmod;
      bfr[nf] = *(const bf16v8*)(smem + 16384 + cur * 8192 + rr * 64 +
                    ((ldiv * 16) ^ ((rr & 3) << 4)));
    }
#pragma unroll
    for (int mf = 0; mf < 4; ++mf)
#pragma unroll
      for (int nf = 0; nf < 4; ++nf)
        acc[mf][nf] = MFMA16(af[mf], bfr[nf], acc[mf][nf]);
  }

  // epilogue: wave's 64-col block is head-aligned
  const int nb = col0 + wn * 64;
  const int proj = nb >> 10;            // 0=q 1=k 2=v  (block-uniform)
  const int hh = (nb & 1023) >> 6;      // head
  if (proj < 2) {
    u16* dst = proj ? ko : qo;
#pragma unroll
    for (int mf = 0; mf < 4; ++mf) {
#pragma unroll
      for (int r = 0; r < 4; ++r) {
        const int m = row0 + wm * 64 + mf * 16 + ldiv * 4 + r;
        const int b = m >> 11, t = m & 2047;
        u16* drow = dst + ((size_t)(b * H_ + hh) * T_ + t) * 64;
#pragma unroll
        for (int nf = 0; nf < 4; ++nf) {
          const int d = nf * 16 + lmod;
          const float cs = cosT[t * 64 + d];
          const float sn = sinT[t * 64 + d];
          const float other = (nf < 2) ? acc[mf][nf + 2][r] : acc[mf][nf - 2][r];
          float val = (nf < 2) ? (acc[mf][nf][r] * cs - other * sn)
                               : (acc[mf][nf][r] * cs + other * sn);
          if (proj == 0) val *= 0.18033688011112042f;  // 0.125 * log2(e)
          drow[d] = f2bf(val);
        }
      }
    }
  } else {
    // V^T direct: LDS bounce [d][t] (XOR-swizzled), then coalesced 128B rows
    BARRIER();                          // everyone done with the ring
    char* scr = smem + w * 8192;        // 8 KB per wave (spans As+Bs)
#pragma unroll
    for (int nf = 0; nf < 4; ++nf)
#pragma unroll
      for (int mf = 0; mf < 4; ++mf)
#pragma unroll
        for (int rp = 0; rp < 2; ++rp) {
          const int dd = nf * 16 + lmod;
          const int t0 = mf * 16 + ldiv * 4 + rp * 2;
          const uint32_t pk = (uint32_t)f2bf(acc[mf][nf][rp * 2]) |
                              ((uint32_t)f2bf(acc[mf][nf][rp * 2 + 1]) << 16);
          *(uint32_t*)(scr + ((dd * 128 + t0 * 2) ^ ((dd & 7) << 4))) = pk;
        }
    __syncthreads();
    const int trow = row0 + wm * 64;    // this wave's 64 t-values
    const int bb = trow >> 11, tl = trow & 2047;
#pragma unroll
    for (int j = 0; j < 8; ++j) {
      const int dd = j * 8 + (lane >> 3);
      const int c = lane & 7;
      const u32x4 vv = *(const u32x4*)(scr + ((dd * 128 + c * 16) ^ ((dd & 7) << 4)));
      u16* drow = vt + ((size_t)((bb * H_ + hh) * 64 + dd)) * T_ + tl;
      *(u32x4*)((char*)drow + c * 16) = vv;
    }
  }
}

// ---------------------------------------------------------------- GEMM 128x128
// (R13-proven BK=64 template; used for the output projection only.)
template<int NN>
__global__ __launch_bounds__(256, 2) void gemm128(
    const u16* __restrict__ A, const u16* __restrict__ Bm,
    float* __restrict__ Cf)
{
  __shared__ __align__(16) u16 As[2][128 * 64];   // 32 KiB
  __shared__ __align__(16) u16 Bs[2][128 * 64];   // 32 KiB
  const int tid = threadIdx.x;
  const int lane = tid & 63;
  const int w = tid >> 6;
  const int wm = w >> 1, wn = w & 1;
  const int lmod = lane & 15, ldiv = lane >> 4;

  const int x = blockIdx.x & 7;
  const int i = blockIdx.x >> 3;
  const int by = x * 4 + (i % 4);
  const int bx = i / 4;
  const int row0 = by * 128, col0 = bx * 128;

  const int srow = tid >> 3;                      // 0..31
  const int sswz = ((tid & 7) * 16) ^ ((srow & 7) << 4);
  const char* Abase = (const char*)A + (size_t)(row0 + srow) * (KDIM * 2) + sswz;
  const char* Bbase = (const char*)Bm + (size_t)(col0 + srow) * (KDIM * 2) + sswz;
  const int ldst = (tid & 192) * 16;              // wave-uniform LDS sub-base

  auto stage = [&](int buf, int t) {
    const int kb = t * 128;                       // K-tile byte offset in row
#pragma unroll
    for (int c = 0; c < 4; ++c)
      gload16(Abase + (size_t)c * 32 * (KDIM * 2) + kb,
              (char*)As[buf] + c * 4096 + ldst);
#pragma unroll
    for (int c = 0; c < 4; ++c)
      gload16(Bbase + (size_t)c * 32 * (KDIM * 2) + kb,
              (char*)Bs[buf] + c * 4096 + ldst);
  };

  f32x4 acc[4][4] = {};
  stage(0, 0);

  for (int t = 0; t < KDIM / 64; ++t) {
    const int cur = t & 1;
    BARRIER();                                    // all waves done reading buf[cur^1]
    if (t + 1 < KDIM / 64) {
      stage(cur ^ 1, t + 1);                      // 8 loads for t+1 in flight
      asm volatile("s_waitcnt vmcnt(8)" ::: "memory");   // tile t landed
    } else {
      asm volatile("s_waitcnt vmcnt(0)" ::: "memory");
    }
    BARRIER();                                    // cross-wave: tile t visible

    bf16v8 af[4][2], bfr[4][2];
#pragma unroll
    for (int mf = 0; mf < 4; ++mf) {
      const int rr = wm * 64 + mf * 16 + lmod;
#pragma unroll
      for (int kc = 0; kc < 2; ++kc)
        af[mf][kc] = *(const bf16v8*)((const char*)As[cur] + rr * 128 +
                          ((kc * 64 + ldiv * 16) ^ ((rr & 7) << 4)));
    }
#pragma unroll
    for (int nf = 0; nf < 4; ++nf) {
      const int rr = wn * 64 + nf * 16 + lmod;
#pragma unroll
      for (int kc = 0; kc < 2; ++kc)
        bfr[nf][kc] = *(const bf16v8*)((const char*)Bs[cur] + rr * 128 +
                          ((kc * 64 + ldiv * 16) ^ ((rr & 7) << 4)));
    }
#pragma unroll
    for (int kc = 0; kc < 2; ++kc)
#pragma unroll
      for (int mf = 0; mf < 4; ++mf)
#pragma unroll
        for (int nf = 0; nf < 4; ++nf)
          acc[mf][nf] = MFMA16(af[mf][kc], bfr[nf][kc], acc[mf][nf]);
  }

#pragma unroll
  for (int mf = 0; mf < 4; ++mf) {
    const int mbase = row0 + wm * 64 + mf * 16 + ldiv * 4;
#pragma unroll
    for (int nf = 0; nf < 4; ++nf) {
      const int n = col0 + wn * 64 + nf * 16 + lmod;
#pragma unroll
      for (int r = 0; r < 4; ++r)
        Cf[(size_t)(mbase + r) * NN + n] = acc[mf][nf][r];
    }
  }
}

// ---------------------------------------------------------------- attention
// Split-K flash attention (R17/R18 proven: heavy-first LPT dispatch, vmcnt(4),
// KVBLK=64, separate combine kernel — fused-combine's per-block threadfence
// triggered per-fence L2 writebacks and was 4x slower, R20 lesson).
__global__ __launch_bounds__(256, 2) void attn_fwd4(
    const u16* __restrict__ Q, const u16* __restrict__ K,
    const u16* __restrict__ Vt, u16* __restrict__ O,
    u16* __restrict__ part_o, float* __restrict__ pml)
{
  __shared__ __align__(16) u16 Kl[2][64 * 64];    // 8 KiB per buffer
  __shared__ __align__(16) u16 Vl[2][64 * 64];
  static const int rmap[24] = {7, 22, 23, 20, 21, 6, 18, 19, 16, 17, 5, 14,
                               15, 12, 13, 4, 10, 11, 8, 9, 3, 2, 1, 0};
  const int xcd = blockIdx.x & 7;
  const int i   = blockIdx.x >> 3;          // 0..95
  const int bh  = xcd * 4 + (i & 3);
  const int r   = rmap[i >> 2];             // heavy classes first
  int qb0, t0, t1, sid;
  if (r < 8) {                              // whole chunk c = r
    qb0 = r * 128; t0 = 0; t1 = 2 * r + 2; sid = -1;
  } else {                                  // split half of chunk c = 8+(s>>1)
    const int s = r - 8;                    // 0..15
    const int c = 8 + (s >> 1);
    const int half = s & 1;
    qb0 = c * 128;
    t0 = half * (c + 1); t1 = t0 + (c + 1);
    sid = (bh * 8 + (c - 8)) * 2 + half;
  }

  const int tid = threadIdx.x, lane = tid & 63, w = tid >> 6;
  const int l31 = lane & 31, hi = lane >> 5;
  const int qrow = qb0 + w * 32;

  bf16v8 qf[4];
  {
    const u16* qp = Q + ((size_t)bh * T_ + qrow + l31) * 64 + hi * 8;
    qf[0] = *(const bf16v8*)(qp);
    qf[1] = *(const bf16v8*)(qp + 16);
    qf[2] = *(const bf16v8*)(qp + 32);
    qf[3] = *(const bf16v8*)(qp + 48);
  }

  float m2 = -1e30f, lsum = 0.f;            // log2-domain running max / sum
  f32x16 oacc0 = {}, oacc1 = {};            // O^T d-blocks 0..31 / 32..63

  const int scolb = (tid & 7) * 16;         // 16B col within 128B row
  const int ldst = (tid & 192) * 16;        // wave-uniform LDS sub-base

  auto stage = [&](int buf, int t) {
    const int s0 = t << 6;
#pragma unroll
    for (int c = 0; c < 2; ++c) {
      const int row = (c * 256 + tid) >> 3;
      const int sw = scolb ^ ((row & 7) << 4);
      gload16((const char*)(K + ((size_t)bh * T_ + s0 + row) * 64) + sw,
              (char*)Kl[buf] + c * 4096 + ldst);
    }
#pragma unroll
    for (int c = 0; c < 2; ++c) {
      const int row = (c * 256 + tid) >> 3;
      const int sw = scolb ^ ((row & 7) << 4);
      gload16((const char*)(Vt + ((size_t)(bh * 64 + row)) * T_ + s0) + sw,
              (char*)Vl[buf] + c * 4096 + ldst);
    }
  };

  auto substep = [&](int cur, int sub, int s0_sub) {
    bf16v8 kf[4], vf[4];
#pragma unroll
    for (int c = 0; c < 4; ++c) {
      const int row = sub * 32 + l31;
      kf[c] = *(const bf16v8*)((const char*)Kl[cur] + row * 128 +
                  ((c * 32 + hi * 16) ^ ((row & 7) << 4)));
    }
#pragma unroll
    for (int db = 0; db < 2; ++db)
#pragma unroll
      for (int kg = 0; kg < 2; ++kg) {
        const int row = db * 32 + l31;
        vf[db * 2 + kg] = *(const bf16v8*)((const char*)Vl[cur] + row * 128 +
                  ((sub * 64 + kg * 32 + hi * 16) ^ ((row & 7) << 4)));
      }
    f32x16 s = {};
    s = MFMA32(kf[0], qf[0], s);
    s = MFMA32(kf[1], qf[1], s);
    s = MFMA32(kf[2], qf[2], s);
    s = MFMA32(kf[3], qf[3], s);
    if (s0_sub + 31 > qrow) {               // diagonal substep: causal mask
#pragma unroll
      for (int r2 = 0; r2 < 16; ++r2) {
        const int key = s0_sub + (r2 & 3) + 8 * (r2 >> 2) + 4 * hi;
        if (key > qrow + l31) s[r2] = -1e30f;
      }
    }
    float t8[8];
#pragma unroll
    for (int r2 = 0; r2 < 8; ++r2) t8[r2] = fmaxf(s[r2], s[r2 + 8]);
    float t4a = fmaxf(t8[0], t8[4]), t4b = fmaxf(t8[1], t8[5]);
    float t4c = fmaxf(t8[2], t8[6]), t4d = fmaxf(t8[3], t8[7]);
    float pmax = fmaxf(fmaxf(t4a, t4b), fmaxf(t4c, t4d));
    {
      uint32_t lo, hh2;
      xhalf(__builtin_bit_cast(uint32_t, pmax), __builtin_bit_cast(uint32_t, pmax), lo, hh2);
      pmax = fmaxf(__builtin_bit_cast(float, lo), __builtin_bit_cast(float, hh2));
    }
    if (!__all(pmax <= m2 + 11.5416f)) {    // defer-max THR = 8*log2e
      const float mnew = fmaxf(m2, pmax);
      const float rs = __builtin_amdgcn_exp2f(m2 - mnew);
      lsum *= rs;
#pragma unroll
      for (int r2 = 0; r2 < 16; ++r2) { oacc0[r2] *= rs; oacc1[r2] *= rs; }
      m2 = mnew;
    }
    float p[16];
#pragma unroll
    for (int r2 = 0; r2 < 16; ++r2) p[r2] = __builtin_amdgcn_exp2f(s[r2] - m2);
    float a8[8];
#pragma unroll
    for (int r2 = 0; r2 < 8; ++r2) a8[r2] = p[r2] + p[r2 + 8];
    float a4a = a8[0] + a8[4], a4b = a8[1] + a8[5];
    float a4c = a8[2] + a8[6], a4d = a8[3] + a8[7];
    float ts = (a4a + a4b) + (a4c + a4d);
    {
      uint32_t lo, hh2;
      xhalf(__builtin_bit_cast(uint32_t, ts), __builtin_bit_cast(uint32_t, ts), lo, hh2);
      ts = __builtin_bit_cast(float, lo) + __builtin_bit_cast(float, hh2);
    }
    lsum += ts;
    uint32_t o[8];
#pragma unroll
    for (int jj = 0; jj < 8; ++jj) {
      const int r0 = 4 * (jj >> 1) + 2 * (jj & 1);
      uint32_t d;
      asm("v_cvt_pk_bf16_f32 %0, %1, %2" : "=v"(d) : "v"(p[r0]), "v"(p[r0 + 1]));
      o[jj] = d;
    }
#pragma unroll
    for (int kg = 0; kg < 2; ++kg) {
      uint32_t f0, f1, f2, f3;
      xhalf(o[4 * kg + 0], o[4 * kg + 2], f0, f2);
      xhalf(o[4 * kg + 1], o[4 * kg + 3], f1, f3);
      u32x4 fr;
      fr.x = f0; fr.y = f1; fr.z = f2; fr.w = f3;
      const bf16v8 pf = __builtin_bit_cast(bf16v8, fr);
      oacc0 = MFMA32(vf[kg], pf, oacc0);
      oacc1 = MFMA32(vf[2 + kg], pf, oacc1);
    }
  };

  stage(0, t0);
  for (int t = t0; t < t1; ++t) {
    const int cur = (t - t0) & 1;
    BARRIER();
    if (t + 1 < t1) {
      stage(cur ^ 1, t + 1);
      asm volatile("s_waitcnt vmcnt(4)" ::: "memory");   // tile t's 4 landed
    } else {
      asm volatile("s_waitcnt vmcnt(0)" ::: "memory");
    }
    BARRIER();
#pragma unroll
    for (int sub = 0; sub < 2; ++sub) {
      const int s0_sub = t * 64 + sub * 32;
      if (s0_sub <= qrow + 31) substep(cur, sub, s0_sub);
    }
  }

  BARRIER();                                // all waves done with Kl/Vl
  char* scr = (char*)Kl + w * 4096;         // 4 KB per wave: [q=32][d=64] bf16
  const float inv = (sid < 0) ? (1.f / lsum) : 1.f;
#pragma unroll
  for (int r2 = 0; r2 < 8; ++r2) {
    const int r = r2 * 2;                   // regs r, r+1 are adjacent d
    const int dd = (r & 3) + 8 * (r >> 2) + 4 * hi;
    const uint32_t pk0 = (uint32_t)f2bf(oacc0[r] * inv) |
                         ((uint32_t)f2bf(oacc0[r + 1] * inv) << 16);
    *(uint32_t*)(scr + ((l31 * 128 + dd * 2) ^ ((l31 & 7) << 4))) = pk0;
    const uint32_t pk1 = (uint32_t)f2bf(oacc1[r] * inv) |
                         ((uint32_t)f2bf(oacc1[r + 1] * inv) << 16);
    *(uint32_t*)(scr + ((l31 * 128 + (dd + 32) * 2) ^ ((l31 & 7) << 4))) = pk1;
  }
  __syncthreads();
  const int qq = lane >> 1, cc = lane & 1;  // 2 lanes per output row
  if (sid < 0) {
    const int b = bh >> 4, hh = bh & 15;
    u16* orow = O + ((size_t)(b * T_ + qrow + qq)) * C_ + hh * 64 + cc * 32;
#pragma unroll
    for (int jj = 0; jj < 4; ++jj) {
      const u32x4 vv = *(const u32x4*)(scr + ((qq * 128 + cc * 64 + jj * 16) ^ ((qq & 7) << 4)));
      *(u32x4*)((char*)orow + jj * 16) = vv;
    }
  } else {
    u16* prow = part_o + ((size_t)(sid * 128 + w * 32 + qq)) * 64 + cc * 32;
#pragma unroll
    for (int jj = 0; jj < 4; ++jj) {
      const u32x4 vv = *(const u32x4*)(scr + ((qq * 128 + cc * 64 + jj * 16) ^ ((qq & 7) << 4)));
      *(u32x4*)((char*)prow + jj * 16) = vv;
    }
    if (lane < 32) {                        // lanes 0..31: one per q-row
      pml[sid * 256 + w * 32 + lane] = m2;
      pml[sid * 256 + 128 + w * 32 + lane] = lsum;
    }
  }
}

// ---------------------------------------------------------------- combine
__global__ __launch_bounds__(256) void attn_combine(
    const u16* __restrict__ part_o, const float* __restrict__ pml,
    u16* __restrict__ O)
{
  const int combo = blockIdx.x;             // 0..255 = (bh, c-8)
  const int bh = combo >> 3, c8 = combo & 7;
  const int sid0 = (bh * 8 + c8) * 2;
  const int row = threadIdx.x >> 1, dh = threadIdx.x & 1;
  const float m0 = pml[sid0 * 256 + row];
  const float l0 = pml[sid0 * 256 + 128 + row];
  const float m1 = pml[(sid0 + 1) * 256 + row];
  const float l1 = pml[(sid0 + 1) * 256 + 128 + row];
  const float m = fmaxf(m0, m1);
  const float s0 = __builtin_amdgcn_exp2f(m0 - m);
  const float s1 = __builtin_amdgcn_exp2f(m1 - m);
  const float inv = 1.f / (l0 * s0 + l1 * s1);
  const u16* p0 = part_o + ((size_t)(sid0 * 128 + row)) * 64 + dh * 32;
  const u16* p1 = part_o + ((size_t)((sid0 + 1) * 128 + row)) * 64 + dh * 32;
  const int b = bh >> 4, hh = bh & 15;
  const int t = (8 + c8) * 128 + row;
  u16* dst = O + ((size_t)(b * T_ + t)) * C_ + hh * 64 + dh * 32;
#pragma unroll
  for (int j0 = 0; j0 < 4; ++j0) {
    const u32x4 a = *(const u32x4*)(p0 + j0 * 8);
    const u32x4 bq = *(const u32x4*)(p1 + j0 * 8);
    const u16* pa = (const u16*)&a;
    const u16* pb = (const u16*)&bq;
    u16 outv[8];
#pragma unroll
    for (int j = 0; j < 8; ++j)
      outv[j] = f2bf((bf2f(pa[j]) * s0 + bf2f(pb[j]) * s1) * inv);
    *(u32x4*)(dst + j0 * 8) = *(const u32x4*)outv;
  }
}

// ---------------------------------------------------------------- launch
extern "C" void kernel_launch(void* const* d_in, const int* in_sizes, int n_in,
                              void* d_out, int out_size, void* d_ws, size_t ws_size,
                              hipStream_t stream) {
  const float* x    = (const float*)d_in[0];
  const float* cosT = (const float*)d_in[1];
  const float* sinT = (const float*)d_in[2];
  // d_in[3] = mask (causal by construction, unused), d_in[4] = n_heads (=16)
  const float* Wq = (const float*)d_in[5];
  const float* Wk = (const float*)d_in[6];
  const float* Wv = (const float*)d_in[7];
  const float* Wo = (const float*)d_in[8];
  float* out = (float*)d_out;

  // workspace layout (48 MB total)
  char* ws = (char*)d_ws;
  u16* xb   = (u16*)(ws);                    // bf16 x; partials alias after gemm1
  u16* wqkv = (u16*)(ws + 8388608);          // [Wq;Wk;Wv] bf16; pml aliases tail
  u16* wo   = (u16*)(ws + 14680064);         // Wo bf16
  u16* q    = (u16*)(ws + 16777216);         // (B,H,T,64) bf16, roped+scaled
  u16* k    = (u16*)(ws + 25165824);         // (B,H,T,64) bf16, roped
  u16* vt   = (u16*)(ws + 33554432);         // (B,H,64,T) bf16 (direct from gemm)
  u16* aout = (u16*)(ws + 41943040);         // attention output (B,T,C) bf16
  u16* part_o = xb;                          // 512*128*64 bf16 = 8 MB (xb dead)
  float* pml  = (float*)(ws + 8388608);      // 512*256 fp32 = 0.5 MB (wqkv dead)

  cvt_all<<<8192, 256, 0, stream>>>(x, Wq, Wk, Wv, Wo, xb, wqkv, wo);

  gemm_qkv32<<<768, 256, 0, stream>>>(xb, wqkv, q, k, vt, cosT, sinT);
  attn_fwd4<<<768, 256, 0, stream>>>(q, k, vt, aout, part_o, pml);
  attn_combine<<<256, 256, 0, stream>>>(part_o, pml, aout);
  gemm128<1024><<<256, 256, 0, stream>>>(aout, wo, out);
}